// Round 8
// baseline (214.997 us; speedup 1.0000x reference)
//
#include <hip/hip_runtime.h>

#define HW 4096
#define CC 128
#define MARGIN 2e-3f

typedef unsigned short ushort_t;
typedef unsigned int uint_t;
typedef __attribute__((ext_vector_type(8))) short short8;
typedef __attribute__((ext_vector_type(4))) float f32x4;

__device__ __forceinline__ float dot4(float4 a, float4 b) {
    return (a.x*b.x + a.y*b.y) + (a.z*b.z + a.w*b.w);
}

__device__ __forceinline__ ushort_t f2bf(float f) {
    union { float f; uint_t u; } cv; cv.f = f;
    uint_t r = cv.u + 0x7fffu + ((cv.u >> 16) & 1u);
    return (ushort_t)(r >> 16);
}

__device__ __forceinline__ float bf2f(ushort_t h) {
    union { uint_t u; float f; } cv; cv.u = ((uint_t)h) << 16;
    return cv.f;
}

__device__ __forceinline__ void store16(ushort_t* dst, const ushort_t* s) {
    union { ushort_t s[8]; uint4 v; } a, b;
    #pragma unroll
    for (int j = 0; j < 8; j++) { a.s[j] = s[j]; b.s[j] = s[8+j]; }
    *(uint4*)dst = a.v;
    *(uint4*)(dst + 8) = b.v;
}

__device__ __forceinline__ void gl2lds16(const ushort_t* g, ushort_t* l) {
    __builtin_amdgcn_global_load_lds(
        (const __attribute__((address_space(1))) unsigned int*)g,
        (__attribute__((address_space(3))) unsigned int*)l, 16, 0, 0);
}

// ---------- Kernel 1: fused prep (qk+split | xt | border | wt) ----------
// grid 658: [0,128) qk, [128,384) xt, [384,514) border, [514,658) wt
// qk weights read directly from global: wave-uniform address -> s_load (SMEM pipe)
__global__ __launch_bounds__(256) void prep_kernel(
    const float* __restrict__ x, const float* __restrict__ xf,
    const float* __restrict__ Wq, const float* __restrict__ bq,
    const float* __restrict__ Wk, const float* __restrict__ bk,
    const float* __restrict__ Wf,
    float* __restrict__ Qt, float* __restrict__ Kt,
    ushort_t* __restrict__ Qs, ushort_t* __restrict__ KB,
    ushort_t* __restrict__ xsel, ushort_t* __restrict__ Wt)
{
    __shared__ __align__(16) unsigned char smem[16704];
    int bid = blockIdx.x;
    int tid = threadIdx.x;

    if (bid < 128) {
        // ---- qk: Q/K 1x1 conv -> Qt/Kt f32 [b][p][16] + fused bf16 split ----
        bool isQ = bid < 64;
        const float* src  = isQ ? xf : x;
        const float* W    = isQ ? Wq : Wk;
        const float* bias = isQ ? bq : bk;

        int pg = (bid & 63) * 256 + tid;          // b*4096 + p
        int b = pg >> 12, p = pg & 4095;
        const float* sp = src + ((size_t)b << 19) + p;

        float acc[16];
        #pragma unroll
        for (int o = 0; o < 16; o++) acc[o] = bias[o];   // uniform -> s_load

        for (int c4 = 0; c4 < 128; c4 += 4) {
            float x0 = sp[(size_t)(c4+0) << 12];
            float x1 = sp[(size_t)(c4+1) << 12];
            float x2 = sp[(size_t)(c4+2) << 12];
            float x3 = sp[(size_t)(c4+3) << 12];
            #pragma unroll
            for (int o = 0; o < 16; o++) {
                float4 w = *(const float4*)&W[o*128 + c4];   // uniform -> s_load
                acc[o] += w.x*x0 + w.y*x1 + w.z*x2 + w.w*x3;
            }
        }

        float* dstF = isQ ? Qt : Kt;
        float4* df = (float4*)(dstF + (size_t)pg * 16);
        df[0] = make_float4(acc[0],acc[1],acc[2],acc[3]);
        df[1] = make_float4(acc[4],acc[5],acc[6],acc[7]);
        df[2] = make_float4(acc[8],acc[9],acc[10],acc[11]);
        df[3] = make_float4(acc[12],acc[13],acc[14],acc[15]);

        ushort_t h[16], m[16], l[16];
        #pragma unroll
        for (int d = 0; d < 16; d++) {
            h[d] = f2bf(acc[d]);
            float r1 = acc[d] - bf2f(h[d]);
            m[d] = f2bf(r1);
            l[d] = f2bf(r1 - bf2f(m[d]));
        }
        if (isQ) {
            ushort_t* o_ = Qs + (size_t)pg*64;    // [h|m|h|l]
            store16(o_,      h);
            store16(o_ + 16, m);
            store16(o_ + 32, h);
            store16(o_ + 48, l);
        } else {
            int u = b*256 + (p >> 4);
            int n = p & 15;
            ushort_t* o_ = KB + (size_t)u*1536 + n*32;
            store16(o_,        h); store16(o_ + 16,   h);   // pass0 [kh|kh]
            store16(o_ + 512,  m); store16(o_ + 528,  m);   // pass1 [km|km]
            store16(o_ + 1024, l); store16(o_ + 1040, h);   // pass2 [kl|kh]
        }
    } else if (bid < 384) {
        // ---- xt: x f32 [c][y][x] -> xsel[b][y+1][x+1][c] bf16 (c<128) ----
        ushort_t* sT = (ushort_t*)smem;    // 64*130
        int xbid = bid - 128;
        int b = xbid >> 6, y = xbid & 63;
        int cq = tid >> 6, xx = tid & 63;
        const float* src = x + ((size_t)b << 19) + (y << 6) + xx;
        #pragma unroll 4
        for (int k = 0; k < 32; k++) {
            int c = cq*32 + k;
            sT[xx*130 + c] = f2bf(src[(size_t)c << 12]);
        }
        __syncthreads();
        uint_t* dst = (uint_t*)(xsel + ((size_t)(b*4356 + (y+1)*66 + 1))*256);
        #pragma unroll
        for (int k = 0; k < 16; k++) {
            int idx = k*256 + tid;
            int s = idx >> 6, u = idx & 63;
            uint_t v = *(const uint_t*)&sT[s*130 + u*2];
            dst[s*128 + u] = v;
        }
    } else if (bid < 514) {
        // ---- border: zero 66x66 border sites of xsel ----
        int g = (bid - 384) * 256 + tid;
        if (g < 33280) {
            int b = g / 8320;
            int rem = g - b * 8320;
            int si = rem >> 5;
            int ch = rem & 31;
            int y, xx;
            if (si < 66)      { y = 0;  xx = si; }
            else if (si < 132){ y = 65; xx = si - 66; }
            else { int t = si - 132; y = 1 + (t >> 1); xx = (t & 1) ? 65 : 0; }
            int site = y * 66 + xx;
            uint4* dst = (uint4*)(xsel + ((size_t)(b*4356 + site))*256);
            dst[ch] = make_uint4(0,0,0,0);
        }
    } else {
        // ---- wt: Wf f32 -> bf16 [og][cb][tap][o32][ci32] ----
        int t = (bid - 514) * 256 + tid;
        if (t < 36864) {
            int cg = t & 3;
            int o = (t >> 2) & 31;
            int tc = t >> 7;
            int tap = tc % 9;
            int rest = tc / 9;
            int cb = rest & 7, og = rest >> 3;
            union { ushort_t s[8]; uint4 v; } pk;
            #pragma unroll
            for (int j = 0; j < 8; j++) {
                int ci = cg*8 + j;
                pk.s[j] = f2bf(Wf[(size_t)(og*32 + o)*2304 + (cb*32 + ci)*9 + tap]);
            }
            *(uint4*)(Wt + (size_t)t*8) = pk.v;
        }
    }
}

// ---------- Kernel 2: v-section + MFMA max/argmax (packed in one launch) ----------
// grid 640: [0,128) v (independent of qk), [128,640) att; block 512 = 8 waves
__global__ __launch_bounds__(512) void attv_kernel(
    const float* __restrict__ xb, const float* __restrict__ Wv,
    const float* __restrict__ bv, float* __restrict__ V,
    const ushort_t* __restrict__ Qs, const ushort_t* __restrict__ KB,
    float* __restrict__ pm1, int* __restrict__ pi1, float* __restrict__ pm2)
{
    __shared__ float sM1[64*33];
    __shared__ int   sI1[64*33];
    __shared__ float sM2[64*33];

    int bid = blockIdx.x;
    int tid = threadIdx.x;

    if (bid < 128) {
        // ---- v: V = Wv * x_backward + bv, [b][c][p]; weights via s_load ----
        int b = bid >> 5, og = (bid >> 3) & 3, pt = bid & 7;
        int oz = tid >> 8, pz = tid & 255;     // oz wave-uniform (waves 0-3 / 4-7)
        int p = pt*512 + pz*2;
        const float* sp = xb + ((size_t)b << 19) + p;

        float2 acc[16];
        #pragma unroll
        for (int j = 0; j < 16; j++) acc[j] = make_float2(0.f, 0.f);

        for (int c4 = 0; c4 < 128; c4 += 4) {
            float2 x0 = *(const float2*)&sp[(size_t)(c4+0) << 12];
            float2 x1 = *(const float2*)&sp[(size_t)(c4+1) << 12];
            float2 x2 = *(const float2*)&sp[(size_t)(c4+2) << 12];
            float2 x3 = *(const float2*)&sp[(size_t)(c4+3) << 12];
            #pragma unroll
            for (int j = 0; j < 16; j++) {
                float4 w = *(const float4*)&Wv[(og*32 + oz*16 + j)*128 + c4];  // uniform
                acc[j].x += w.x*x0.x + w.y*x1.x + w.z*x2.x + w.w*x3.x;
                acc[j].y += w.x*x0.y + w.y*x1.y + w.z*x2.y + w.w*x3.y;
            }
        }
        #pragma unroll
        for (int j = 0; j < 16; j++) {
            int o = og*32 + oz*16 + j;
            float bb = bv[o];
            float2 r = make_float2(acc[j].x + bb, acc[j].y + bb);
            *(float2*)&V[(((size_t)b*CC + o)<<12) + p] = r;
        }
        return;
    }

    int abid = bid - 128;
    int qh = abid & 1, kg = (abid >> 1) & 63, b = abid >> 7;
    int wave = tid >> 6, lane = tid & 63;
    int l15 = lane & 15, quad = lane >> 4;

    short8 Bf[4][3];
    const ushort_t* kb = KB + ((size_t)((b*256 + kg*4)*3))*512 + l15*32 + quad*8;
    #pragma unroll
    for (int t = 0; t < 4; t++)
        #pragma unroll
        for (int p = 0; p < 3; p++)
            Bf[t][p] = *(const short8*)(kb + (size_t)(t*3 + p)*512);

    const ushort_t* qbase = Qs + ((size_t)(b*4096 + qh*2048 + wave*256 + l15))*64 + quad*8;

    float m1[4], m2[4]; int i1[4];
    #pragma unroll
    for (int t = 0; t < 4; t++) { m1[t] = -1e30f; m2[t] = -1e30f; i1[t] = 0; }

    for (int it = 0; it < 16; it++) {
        const ushort_t* aptr = qbase + it*1024;
        short8 A1 = *(const short8*)aptr;
        short8 A2 = *(const short8*)(aptr + 32);
        f32x4 acc[4];
        #pragma unroll
        for (int t = 0; t < 4; t++) {
            acc[t] = (f32x4)0.f;
            acc[t] = __builtin_amdgcn_mfma_f32_16x16x32_bf16(A1, Bf[t][0], acc[t], 0, 0, 0);
            acc[t] = __builtin_amdgcn_mfma_f32_16x16x32_bf16(A1, Bf[t][1], acc[t], 0, 0, 0);
            acc[t] = __builtin_amdgcn_mfma_f32_16x16x32_bf16(A2, Bf[t][2], acc[t], 0, 0, 0);
        }
        int q0 = qh*2048 + wave*256 + it*16 + quad*4;
        #pragma unroll
        for (int r = 0; r < 4; r++) {
            int cand = q0 + r;
            #pragma unroll
            for (int t = 0; t < 4; t++) {
                float d = acc[t][r];
                float old1 = m1[t];
                bool gt = d > old1;
                m1[t] = gt ? d : old1;
                i1[t] = gt ? cand : i1[t];
                m2[t] = fmaxf(m2[t], fminf(d, old1));
            }
        }
    }

    #pragma unroll
    for (int t = 0; t < 4; t++) {
        int kl_ = t*16 + l15;
        int slot = wave*4 + quad;
        sM1[kl_*33 + slot] = m1[t];
        sI1[kl_*33 + slot] = i1[t];
        sM2[kl_*33 + slot] = m2[t];
    }
    __syncthreads();
    if (tid < 64) {
        float M1 = -1e30f; int I1 = 0x7fffffff;
        for (int s = 0; s < 32; s++) {
            float m = sM1[tid*33 + s]; int i = sI1[tid*33 + s];
            if (m > M1 || (m == M1 && i < I1)) { M1 = m; I1 = i; }
        }
        float M2 = -1e30f;
        for (int s = 0; s < 32; s++) {
            float m = sM1[tid*33 + s]; int i = sI1[tid*33 + s];
            float cnd = (i == I1) ? sM2[tid*33 + s] : m;
            M2 = fmaxf(M2, cnd);
        }
        int out = ((qh*4 + b) << 12) + kg*64 + tid;
        pm1[out] = M1; pi1[out] = I1; pm2[out] = M2;
    }
}

// ---------- Kernel 3: combine halves, flag low-margin rows ----------
__global__ __launch_bounds__(256) void fixup1_kernel(
    const float* __restrict__ pm1, const int* __restrict__ pi1,
    const float* __restrict__ pm2,
    float* __restrict__ maxv, int* __restrict__ idxv,
    int* __restrict__ gN, int* __restrict__ gList)
{
    int row = blockIdx.x*256 + threadIdx.x;
    int b = row >> 12, k = row & 4095;
    float m1a = pm1[(b<<12)+k];     int i1a = pi1[(b<<12)+k];     float m2a = pm2[(b<<12)+k];
    float m1b = pm1[((4+b)<<12)+k]; int i1b = pi1[((4+b)<<12)+k]; float m2b = pm2[((4+b)<<12)+k];
    float M1, ru; int I1;
    if (m1b > m1a) { M1 = m1b; I1 = i1b; ru = fmaxf(m1a, fmaxf(m2a, m2b)); }
    else           { M1 = m1a; I1 = i1a; ru = fmaxf(m1b, fmaxf(m2a, m2b)); }
    maxv[row] = M1; idxv[row] = I1;
    if (M1 - ru < MARGIN) {
        int p = atomicAdd(gN, 1);
        gList[p] = row;
    }
}

// ---------- Kernel 4: exact f32 rescan of flagged rows (parallel reduce) ----------
__global__ __launch_bounds__(256) void fixup2_kernel(
    const float* __restrict__ Qt, const float* __restrict__ Kt,
    const int* __restrict__ gN, const int* __restrict__ gList,
    float* __restrict__ maxv, int* __restrict__ idxv)
{
    __shared__ float sRm[256];
    __shared__ int   sRi[256];
    int n = *gN;
    int tid = threadIdx.x;
    for (int e = blockIdx.x; e < n; e += 64) {
        int r2 = gList[e];
        int b2 = r2 >> 12, k2 = r2 & 4095;
        const float4* Kp = (const float4*)(Kt + ((size_t)(b2*4096 + k2))*16);
        float4 ka = Kp[0], kbv = Kp[1], kc = Kp[2], kd = Kp[3];
        const float4* Qp = (const float4*)(Qt + ((size_t)b2*4096)*16);
        float m = -1e30f; int i = 0;
        #pragma unroll 4
        for (int j = 0; j < 16; j++) {
            int q = tid*16 + j;
            float4 qa = Qp[q*4+0], qb = Qp[q*4+1], qc = Qp[q*4+2], qd = Qp[q*4+3];
            float d = (dot4(ka,qa) + dot4(kbv,qb)) + (dot4(kc,qc) + dot4(kd,qd));
            if (d > m) { m = d; i = q; }
        }
        sRm[tid] = m; sRi[tid] = i;
        __syncthreads();
        #pragma unroll
        for (int s = 128; s > 0; s >>= 1) {
            if (tid < s) {
                float mo = sRm[tid+s]; int io = sRi[tid+s];
                if (mo > sRm[tid] || (mo == sRm[tid] && io < sRi[tid])) {
                    sRm[tid] = mo; sRi[tid] = io;
                }
            }
            __syncthreads();
        }
        if (tid == 0) { maxv[r2] = sRm[0]; idxv[r2] = sRi[0]; }
        __syncthreads();
    }
}

// ---------- Kernel 5: gather V columns -> xsel bf16 ----------
__global__ __launch_bounds__(256) void gather_kernel(
    const float* __restrict__ V, const int* __restrict__ idxv,
    ushort_t* __restrict__ xsel)
{
    int bid = blockIdx.x;
    int b = bid >> 6, pt = bid & 63;
    int tid = threadIdx.x;
    int pp = tid >> 2, cq = tid & 3;
    int p = pt*64 + pp;
    int ip = idxv[(b << 12) + p];
    const float* vb = V + ((size_t)b << 19) + ip;
    int site = ((p >> 6) + 1)*66 + (p & 63) + 1;
    ushort_t* dst = xsel + ((size_t)(b*4356 + site))*256 + 128 + cq*32;
    #pragma unroll
    for (int k = 0; k < 4; k++) {
        union { ushort_t s[8]; uint4 v; } pk;
        #pragma unroll
        for (int j = 0; j < 8; j++) {
            int c = cq*32 + k*8 + j;
            pk.s[j] = f2bf(vb[(size_t)c << 12]);
        }
        *(uint4*)(dst + k*8) = pk.v;
    }
}

// ---------- Kernel 6: 3x3 conv as bf16 MFMA shift-GEMM ----------
__global__ __launch_bounds__(256) void conv_kernel(
    const float* __restrict__ x, const ushort_t* __restrict__ xsel,
    const ushort_t* __restrict__ Wt, const float* __restrict__ bf,
    const float* __restrict__ maxv, float* __restrict__ out)
{
    __shared__ __align__(16) ushort_t sIn[336*32];
    __shared__ __align__(16) ushort_t sW[9*32*32];

    int bid = blockIdx.x;
    int og = bid & 3, tx = (bid >> 2) & 3, ty = (bid >> 4) & 3, b = bid >> 6;
    int tid = threadIdx.x;
    int wave = tid >> 6, lane = tid & 63;
    int l15 = lane & 15, quad = lane >> 4;

    const ushort_t* xsel_base = xsel + ((size_t)(b*4356 + (ty*16)*66 + tx*16))*256;
    const ushort_t* wt_base   = Wt + (size_t)og*8*9216;

    f32x4 acc[4][2];
    #pragma unroll
    for (int mi = 0; mi < 4; mi++)
        #pragma unroll
        for (int ni = 0; ni < 2; ni++) acc[mi][ni] = (f32x4)0.f;

    int l4q = lane >> 2, l4 = lane & 3;

    for (int cb = 0; cb < 8; cb++) {
        if (cb) __syncthreads();
        for (int r = wave; r < 21; r += 4) {
            int site = r*16 + l4q;
            int iy = site / 18, ix = site - iy*18;
            const ushort_t* g = xsel_base + (size_t)(iy*66 + ix)*256 + cb*32 + l4*8;
            gl2lds16(g, &sIn[r*512]);
        }
        for (int r = wave; r < 18; r += 4) {
            const ushort_t* g = wt_base + (size_t)cb*9216 + r*512 + lane*8;
            gl2lds16(g, &sW[r*512]);
        }
        __syncthreads();

        #pragma unroll
        for (int tap = 0; tap < 9; tap++) {
            const int dy = tap / 3, dx = tap % 3;
            short8 B0 = *(const short8*)&sW[(tap*32 +      l15)*32 + quad*8];
            short8 B1 = *(const short8*)&sW[(tap*32 + 16 + l15)*32 + quad*8];
            #pragma unroll
            for (int mi = 0; mi < 4; mi++) {
                int row = wave*4 + mi + dy;
                short8 A = *(const short8*)&sIn[(row*18 + l15 + dx)*32 + quad*8];
                acc[mi][0] = __builtin_amdgcn_mfma_f32_16x16x32_bf16(A, B0, acc[mi][0], 0, 0, 0);
                acc[mi][1] = __builtin_amdgcn_mfma_f32_16x16x32_bf16(A, B1, acc[mi][1], 0, 0, 0);
            }
        }
    }

    int y0 = ty*16, x0 = tx*16;
    const float* xb_ = x   + ((size_t)b << 19);
    float*       ob  = out + ((size_t)b << 19);
    const float* mxb = maxv + (b << 12);
    #pragma unroll
    for (int mi = 0; mi < 4; mi++) {
        int y = y0 + wave*4 + mi;
        int p = (y << 6) + x0 + quad*4;
        float4 mv = *(const float4*)&mxb[p];
        #pragma unroll
        for (int ni = 0; ni < 2; ni++) {
            int o = og*32 + ni*16 + l15;
            float bfo = bf[o];
            float4 xv = *(const float4*)&xb_[((size_t)o << 12) + p];
            float4 r;
            r.x = xv.x + mv.x * (acc[mi][ni][0] + bfo);
            r.y = xv.y + mv.y * (acc[mi][ni][1] + bfo);
            r.z = xv.z + mv.z * (acc[mi][ni][2] + bfo);
            r.w = xv.w + mv.w * (acc[mi][ni][3] + bfo);
            *(float4*)&ob[((size_t)o << 12) + p] = r;
        }
    }
}

extern "C" void kernel_launch(void* const* d_in, const int* in_sizes, int n_in,
                              void* d_out, int out_size, void* d_ws, size_t ws_size,
                              hipStream_t stream) {
    (void)in_sizes; (void)n_in; (void)out_size; (void)ws_size;
    const float* x  = (const float*)d_in[0];
    const float* xf = (const float*)d_in[1];
    const float* xb = (const float*)d_in[2];
    const float* Wq = (const float*)d_in[3];
    const float* bq = (const float*)d_in[4];
    const float* Wk = (const float*)d_in[5];
    const float* bk = (const float*)d_in[6];
    const float* Wv = (const float*)d_in[7];
    const float* bv = (const float*)d_in[8];
    const float* Wf = (const float*)d_in[9];
    const float* bf = (const float*)d_in[10];
    float* out = (float*)d_out;

    float* ws   = (float*)d_ws;
    float* Qt   = ws;                          // 262144 f
    float* Kt   = Qt + 262144;                 // 262144 f
    float* V    = Kt + 262144;                 // 2097152 f
    float* mx   = V  + 2097152;                // 16384 f
    int*   idxv = (int*)(mx + 16384);          // 16384 i
    float* pm1  = (float*)(idxv + 16384);      // 32768 f
    int*   pi1  = (int*)(pm1 + 32768);         // 32768 i
    float* pm2  = (float*)(pi1 + 32768);       // 32768 f
    int*   gN   = (int*)(pm2 + 32768);         // 4 i (pad)
    int*   gList= gN + 4;                      // 16384 i
    ushort_t* Qs   = (ushort_t*)(gList + 16384); // 1048576 sh
    ushort_t* KB   = Qs + 1048576;             // 1572864 sh
    ushort_t* xsel = KB + 1572864;             // 4460544 sh
    ushort_t* Wt   = xsel + 4460544;           // 294912 sh

    hipMemsetAsync(gN, 0, sizeof(int), stream);
    hipLaunchKernelGGL(prep_kernel,   dim3(658), dim3(256), 0, stream,
                       x, xf, Wq, bq, Wk, bk, Wf, Qt, Kt, Qs, KB, xsel, Wt);
    hipLaunchKernelGGL(attv_kernel,   dim3(640), dim3(512), 0, stream,
                       xb, Wv, bv, V, Qs, KB, pm1, pi1, pm2);
    hipLaunchKernelGGL(fixup1_kernel, dim3(64),  dim3(256), 0, stream, pm1, pi1, pm2, mx, idxv, gN, gList);
    hipLaunchKernelGGL(fixup2_kernel, dim3(64),  dim3(256), 0, stream, Qt, Kt, gN, gList, mx, idxv);
    hipLaunchKernelGGL(gather_kernel, dim3(256), dim3(256), 0, stream, V, idxv, xsel);
    hipLaunchKernelGGL(conv_kernel,   dim3(256), dim3(256), 0, stream, x, xsel, Wt, bf, mx, out);
}

// Round 9
// 204.704 us; speedup vs baseline: 1.0503x; 1.0503x over previous
//
#include <hip/hip_runtime.h>

#define HW 4096
#define CC 128
#define MARGIN 2e-3f

typedef unsigned short ushort_t;
typedef unsigned int uint_t;
typedef __attribute__((ext_vector_type(8))) short short8;
typedef __attribute__((ext_vector_type(4))) float f32x4;

__device__ __forceinline__ float dot4(float4 a, float4 b) {
    return (a.x*b.x + a.y*b.y) + (a.z*b.z + a.w*b.w);
}

__device__ __forceinline__ ushort_t f2bf(float f) {
    union { float f; uint_t u; } cv; cv.f = f;
    uint_t r = cv.u + 0x7fffu + ((cv.u >> 16) & 1u);
    return (ushort_t)(r >> 16);
}

__device__ __forceinline__ float bf2f(ushort_t h) {
    union { uint_t u; float f; } cv; cv.u = ((uint_t)h) << 16;
    return cv.f;
}

__device__ __forceinline__ void store16(ushort_t* dst, const ushort_t* s) {
    union { ushort_t s[8]; uint4 v; } a, b;
    #pragma unroll
    for (int j = 0; j < 8; j++) { a.s[j] = s[j]; b.s[j] = s[8+j]; }
    *(uint4*)dst = a.v;
    *(uint4*)(dst + 8) = b.v;
}

__device__ __forceinline__ void gl2lds16(const ushort_t* g, ushort_t* l) {
    __builtin_amdgcn_global_load_lds(
        (const __attribute__((address_space(1))) unsigned int*)g,
        (__attribute__((address_space(3))) unsigned int*)l, 16, 0, 0);
}

// ---------- Kernel 1: fused prep (qk+split | xt | border | wt) ----------
// grid 658: [0,128) qk, [128,384) xt, [384,514) border, [514,658) wt
__global__ __launch_bounds__(256) void prep_kernel(
    const float* __restrict__ x, const float* __restrict__ xf,
    const float* __restrict__ Wq, const float* __restrict__ bq,
    const float* __restrict__ Wk, const float* __restrict__ bk,
    const float* __restrict__ Wf,
    float* __restrict__ Qt, float* __restrict__ Kt,
    ushort_t* __restrict__ Qs, ushort_t* __restrict__ KB,
    ushort_t* __restrict__ xsel, ushort_t* __restrict__ Wt)
{
    __shared__ __align__(16) unsigned char smem[16704];
    int bid = blockIdx.x;
    int tid = threadIdx.x;

    if (bid < 128) {
        // ---- qk: Q/K 1x1 conv -> Qt/Kt f32 [b][p][16] + fused bf16 split ----
        bool isQ = bid < 64;
        const float* src  = isQ ? xf : x;
        const float* W    = isQ ? Wq : Wk;
        const float* bias = isQ ? bq : bk;

        int pg = (bid & 63) * 256 + tid;          // b*4096 + p
        int b = pg >> 12, p = pg & 4095;
        const float* sp = src + ((size_t)b << 19) + p;

        float acc[16];
        #pragma unroll
        for (int o = 0; o < 16; o++) acc[o] = bias[o];   // uniform -> s_load

        for (int c4 = 0; c4 < 128; c4 += 4) {
            float x0 = sp[(size_t)(c4+0) << 12];
            float x1 = sp[(size_t)(c4+1) << 12];
            float x2 = sp[(size_t)(c4+2) << 12];
            float x3 = sp[(size_t)(c4+3) << 12];
            #pragma unroll
            for (int o = 0; o < 16; o++) {
                float4 w = *(const float4*)&W[o*128 + c4];   // uniform -> s_load
                acc[o] += w.x*x0 + w.y*x1 + w.z*x2 + w.w*x3;
            }
        }

        float* dstF = isQ ? Qt : Kt;
        float4* df = (float4*)(dstF + (size_t)pg * 16);
        df[0] = make_float4(acc[0],acc[1],acc[2],acc[3]);
        df[1] = make_float4(acc[4],acc[5],acc[6],acc[7]);
        df[2] = make_float4(acc[8],acc[9],acc[10],acc[11]);
        df[3] = make_float4(acc[12],acc[13],acc[14],acc[15]);

        ushort_t h[16], m[16], l[16];
        #pragma unroll
        for (int d = 0; d < 16; d++) {
            h[d] = f2bf(acc[d]);
            float r1 = acc[d] - bf2f(h[d]);
            m[d] = f2bf(r1);
            l[d] = f2bf(r1 - bf2f(m[d]));
        }
        if (isQ) {
            ushort_t* o_ = Qs + (size_t)pg*64;    // [h|m|h|l]
            store16(o_,      h);
            store16(o_ + 16, m);
            store16(o_ + 32, h);
            store16(o_ + 48, l);
        } else {
            int u = b*256 + (p >> 4);
            int n = p & 15;
            ushort_t* o_ = KB + (size_t)u*1536 + n*32;
            store16(o_,        h); store16(o_ + 16,   h);   // pass0 [kh|kh]
            store16(o_ + 512,  m); store16(o_ + 528,  m);   // pass1 [km|km]
            store16(o_ + 1024, l); store16(o_ + 1040, h);   // pass2 [kl|kh]
        }
    } else if (bid < 384) {
        // ---- xt: x f32 [c][y][x] -> xsel[b][y+1][x+1][c] bf16 (c<128) ----
        ushort_t* sT = (ushort_t*)smem;    // 64*130
        int xbid = bid - 128;
        int b = xbid >> 6, y = xbid & 63;
        int cq = tid >> 6, xx = tid & 63;
        const float* src = x + ((size_t)b << 19) + (y << 6) + xx;
        #pragma unroll 4
        for (int k = 0; k < 32; k++) {
            int c = cq*32 + k;
            sT[xx*130 + c] = f2bf(src[(size_t)c << 12]);
        }
        __syncthreads();
        uint_t* dst = (uint_t*)(xsel + ((size_t)(b*4356 + (y+1)*66 + 1))*256);
        #pragma unroll
        for (int k = 0; k < 16; k++) {
            int idx = k*256 + tid;
            int s = idx >> 6, u = idx & 63;
            uint_t v = *(const uint_t*)&sT[s*130 + u*2];
            dst[s*128 + u] = v;
        }
    } else if (bid < 514) {
        // ---- border: zero 66x66 border sites of xsel ----
        int g = (bid - 384) * 256 + tid;
        if (g < 33280) {
            int b = g / 8320;
            int rem = g - b * 8320;
            int si = rem >> 5;
            int ch = rem & 31;
            int y, xx;
            if (si < 66)      { y = 0;  xx = si; }
            else if (si < 132){ y = 65; xx = si - 66; }
            else { int t = si - 132; y = 1 + (t >> 1); xx = (t & 1) ? 65 : 0; }
            int site = y * 66 + xx;
            uint4* dst = (uint4*)(xsel + ((size_t)(b*4356 + site))*256);
            dst[ch] = make_uint4(0,0,0,0);
        }
    } else {
        // ---- wt: Wf f32 -> bf16 [og][cb][tap][o32][ci32] ----
        int t = (bid - 514) * 256 + tid;
        if (t < 36864) {
            int cg = t & 3;
            int o = (t >> 2) & 31;
            int tc = t >> 7;
            int tap = tc % 9;
            int rest = tc / 9;
            int cb = rest & 7, og = rest >> 3;
            union { ushort_t s[8]; uint4 v; } pk;
            #pragma unroll
            for (int j = 0; j < 8; j++) {
                int ci = cg*8 + j;
                pk.s[j] = f2bf(Wf[(size_t)(og*32 + o)*2304 + (cb*32 + ci)*9 + tap]);
            }
            *(uint4*)(Wt + (size_t)t*8) = pk.v;
        }
    }
}

// ---------- Kernel 2: V = Wv * x_backward + bv -> position-major [b][p][c] ----------
// grid 256 = b(4) x og(4) x pt(16); block 256 = oz(2) x pz(128); LDS weights
__global__ __launch_bounds__(256) void v_kernel(
    const float* __restrict__ xb, const float* __restrict__ Wv,
    const float* __restrict__ bv, float* __restrict__ V)
{
    __shared__ __align__(16) float sW[32*128];
    int bid = blockIdx.x;
    int b = bid >> 6, og = (bid >> 4) & 3, pt = bid & 15;
    int tid = threadIdx.x;
    for (int e = tid; e < 4096; e += 256) sW[e] = Wv[og*4096 + e];
    __syncthreads();

    int oz = tid >> 7, pz = tid & 127;
    int p0 = pt*256 + pz, p1 = p0 + 128;
    const float* sp = xb + ((size_t)b << 19);

    float acc0[16], acc1[16];
    #pragma unroll
    for (int j = 0; j < 16; j++) { acc0[j] = 0.f; acc1[j] = 0.f; }

    for (int c4 = 0; c4 < 128; c4 += 4) {
        float a0 = sp[((size_t)(c4+0)<<12) + p0], a1 = sp[((size_t)(c4+1)<<12) + p0];
        float a2 = sp[((size_t)(c4+2)<<12) + p0], a3 = sp[((size_t)(c4+3)<<12) + p0];
        float b0 = sp[((size_t)(c4+0)<<12) + p1], b1 = sp[((size_t)(c4+1)<<12) + p1];
        float b2 = sp[((size_t)(c4+2)<<12) + p1], b3 = sp[((size_t)(c4+3)<<12) + p1];
        #pragma unroll
        for (int j = 0; j < 16; j++) {
            float4 w = *(const float4*)&sW[(oz*16 + j)*128 + c4];
            acc0[j] += w.x*a0 + w.y*a1 + w.z*a2 + w.w*a3;
            acc1[j] += w.x*b0 + w.y*b1 + w.z*b2 + w.w*b3;
        }
    }
    int obase = og*32 + oz*16;
    float* r0 = V + ((size_t)((b<<12) + p0))*128 + obase;
    float* r1 = V + ((size_t)((b<<12) + p1))*128 + obase;
    #pragma unroll
    for (int jq = 0; jq < 4; jq++) {
        float b0v = bv[obase + jq*4 + 0], b1v = bv[obase + jq*4 + 1];
        float b2v = bv[obase + jq*4 + 2], b3v = bv[obase + jq*4 + 3];
        *(float4*)(r0 + jq*4) = make_float4(acc0[jq*4]+b0v, acc0[jq*4+1]+b1v, acc0[jq*4+2]+b2v, acc0[jq*4+3]+b3v);
        *(float4*)(r1 + jq*4) = make_float4(acc1[jq*4]+b0v, acc1[jq*4+1]+b1v, acc1[jq*4+2]+b2v, acc1[jq*4+3]+b3v);
    }
}

// ---------- Kernel 3: MFMA max/argmax over ALL q; writes maxv/idxv + flags ----------
// grid 256 = b(4) x kg(64); block 512 = 8 waves; block: 64 k x 4096 q.
__global__ __launch_bounds__(512, 2) void att_kernel(
    const ushort_t* __restrict__ Qs, const ushort_t* __restrict__ KB,
    float* __restrict__ maxv, int* __restrict__ idxv,
    int* __restrict__ gN, int* __restrict__ gList)
{
    __shared__ float sM1[64*33];
    __shared__ int   sI1[64*33];
    __shared__ float sM2[64*33];

    int bid = blockIdx.x;
    int kg = bid & 63, b = bid >> 6;
    int tid = threadIdx.x;
    int wave = tid >> 6, lane = tid & 63;
    int l15 = lane & 15, quad = lane >> 4;

    short8 Bf[4][3];
    const ushort_t* kb = KB + ((size_t)((b*256 + kg*4)*3))*512 + l15*32 + quad*8;
    #pragma unroll
    for (int t = 0; t < 4; t++)
        #pragma unroll
        for (int p = 0; p < 3; p++)
            Bf[t][p] = *(const short8*)(kb + (size_t)(t*3 + p)*512);

    const ushort_t* qbase = Qs + ((size_t)(b*4096 + wave*512 + l15))*64 + quad*8;

    float m1[4], m2[4]; int i1[4];
    #pragma unroll
    for (int t = 0; t < 4; t++) { m1[t] = -1e30f; m2[t] = -1e30f; i1[t] = 0; }

    for (int it = 0; it < 32; it++) {
        const ushort_t* aptr = qbase + it*1024;        // 16 rows x 64 sh
        short8 A1 = *(const short8*)aptr;              // [qh|qm] slice
        short8 A2 = *(const short8*)(aptr + 32);       // [qh|ql] slice
        f32x4 acc[4];
        #pragma unroll
        for (int t = 0; t < 4; t++) {
            acc[t] = (f32x4)0.f;
            acc[t] = __builtin_amdgcn_mfma_f32_16x16x32_bf16(A1, Bf[t][0], acc[t], 0, 0, 0);
            acc[t] = __builtin_amdgcn_mfma_f32_16x16x32_bf16(A1, Bf[t][1], acc[t], 0, 0, 0);
            acc[t] = __builtin_amdgcn_mfma_f32_16x16x32_bf16(A2, Bf[t][2], acc[t], 0, 0, 0);
        }
        int q0 = wave*512 + it*16 + quad*4;
        #pragma unroll
        for (int r = 0; r < 4; r++) {
            int cand = q0 + r;
            #pragma unroll
            for (int t = 0; t < 4; t++) {
                float d = acc[t][r];
                float old1 = m1[t];
                bool gt = d > old1;                 // ascending q within stream
                m1[t] = gt ? d : old1;
                i1[t] = gt ? cand : i1[t];
                m2[t] = __builtin_amdgcn_fmed3f(d, old1, m2[t]);  // new 2nd-max
            }
        }
    }

    #pragma unroll
    for (int t = 0; t < 4; t++) {
        int kl_ = t*16 + l15;
        int slot = wave*4 + quad;
        sM1[kl_*33 + slot] = m1[t];
        sI1[kl_*33 + slot] = i1[t];
        sM2[kl_*33 + slot] = m2[t];
    }
    __syncthreads();
    if (tid < 64) {
        float M1 = -1e30f; int I1 = 0x7fffffff;
        for (int s = 0; s < 32; s++) {
            float m = sM1[tid*33 + s]; int i = sI1[tid*33 + s];
            if (m > M1 || (m == M1 && i < I1)) { M1 = m; I1 = i; }
        }
        float M2 = -1e30f;
        for (int s = 0; s < 32; s++) {
            float m = sM1[tid*33 + s]; int i = sI1[tid*33 + s];
            float cnd = (i == I1) ? sM2[tid*33 + s] : m;
            M2 = fmaxf(M2, cnd);
        }
        int row = (b << 12) + kg*64 + tid;
        maxv[row] = M1; idxv[row] = I1;
        if (M1 - M2 < MARGIN) {
            int p = atomicAdd(gN, 1);
            gList[p] = row;
        }
    }
}

// ---------- Kernel 4: exact f32 rescan of flagged rows (parallel reduce) ----------
__global__ __launch_bounds__(256) void fixup2_kernel(
    const float* __restrict__ Qt, const float* __restrict__ Kt,
    const int* __restrict__ gN, const int* __restrict__ gList,
    float* __restrict__ maxv, int* __restrict__ idxv)
{
    __shared__ float sRm[256];
    __shared__ int   sRi[256];
    int n = *gN;
    int tid = threadIdx.x;
    for (int e = blockIdx.x; e < n; e += 64) {
        int r2 = gList[e];
        int b2 = r2 >> 12, k2 = r2 & 4095;
        const float4* Kp = (const float4*)(Kt + ((size_t)(b2*4096 + k2))*16);
        float4 ka = Kp[0], kbv = Kp[1], kc = Kp[2], kd = Kp[3];
        const float4* Qp = (const float4*)(Qt + ((size_t)b2*4096)*16);
        float m = -1e30f; int i = 0;
        #pragma unroll 4
        for (int j = 0; j < 16; j++) {
            int q = tid*16 + j;
            float4 qa = Qp[q*4+0], qb = Qp[q*4+1], qc = Qp[q*4+2], qd = Qp[q*4+3];
            float d = (dot4(ka,qa) + dot4(kbv,qb)) + (dot4(kc,qc) + dot4(kd,qd));
            if (d > m) { m = d; i = q; }
        }
        sRm[tid] = m; sRi[tid] = i;
        __syncthreads();
        #pragma unroll
        for (int s = 128; s > 0; s >>= 1) {
            if (tid < s) {
                float mo = sRm[tid+s]; int io = sRi[tid+s];
                if (mo > sRm[tid] || (mo == sRm[tid] && io < sRi[tid])) {
                    sRm[tid] = mo; sRi[tid] = io;
                }
            }
            __syncthreads();
        }
        if (tid == 0) { maxv[r2] = sRm[0]; idxv[r2] = sRi[0]; }
        __syncthreads();
    }
}

// ---------- Kernel 5: gather V rows (pos-major) -> xsel bf16 ----------
__global__ __launch_bounds__(256) void gather_kernel(
    const float* __restrict__ V, const int* __restrict__ idxv,
    ushort_t* __restrict__ xsel)
{
    int bid = blockIdx.x;
    int b = bid >> 6, pt = bid & 63;
    int tid = threadIdx.x;
    int pp = tid >> 2, cq = tid & 3;
    int p = pt*64 + pp;
    int ip = idxv[(b << 12) + p];
    const float* vrow = V + ((size_t)((b << 12) + ip))*128 + cq*32;
    int site = ((p >> 6) + 1)*66 + (p & 63) + 1;
    ushort_t* dst = xsel + ((size_t)(b*4356 + site))*256 + 128 + cq*32;
    #pragma unroll
    for (int k = 0; k < 4; k++) {
        float4 a = *(const float4*)(vrow + k*8);
        float4 c = *(const float4*)(vrow + k*8 + 4);
        union { ushort_t s[8]; uint4 v; } pk;
        pk.s[0] = f2bf(a.x); pk.s[1] = f2bf(a.y); pk.s[2] = f2bf(a.z); pk.s[3] = f2bf(a.w);
        pk.s[4] = f2bf(c.x); pk.s[5] = f2bf(c.y); pk.s[6] = f2bf(c.z); pk.s[7] = f2bf(c.w);
        *(uint4*)(dst + k*8) = pk.v;
    }
}

// ---------- Kernel 6: 3x3 conv as bf16 MFMA shift-GEMM ----------
__global__ __launch_bounds__(256) void conv_kernel(
    const float* __restrict__ x, const ushort_t* __restrict__ xsel,
    const ushort_t* __restrict__ Wt, const float* __restrict__ bf,
    const float* __restrict__ maxv, float* __restrict__ out)
{
    __shared__ __align__(16) ushort_t sIn[336*32];
    __shared__ __align__(16) ushort_t sW[9*32*32];

    int bid = blockIdx.x;
    int og = bid & 3, tx = (bid >> 2) & 3, ty = (bid >> 4) & 3, b = bid >> 6;
    int tid = threadIdx.x;
    int wave = tid >> 6, lane = tid & 63;
    int l15 = lane & 15, quad = lane >> 4;

    const ushort_t* xsel_base = xsel + ((size_t)(b*4356 + (ty*16)*66 + tx*16))*256;
    const ushort_t* wt_base   = Wt + (size_t)og*8*9216;

    f32x4 acc[4][2];
    #pragma unroll
    for (int mi = 0; mi < 4; mi++)
        #pragma unroll
        for (int ni = 0; ni < 2; ni++) acc[mi][ni] = (f32x4)0.f;

    int l4q = lane >> 2, l4 = lane & 3;

    for (int cb = 0; cb < 8; cb++) {
        if (cb) __syncthreads();
        for (int r = wave; r < 21; r += 4) {
            int site = r*16 + l4q;
            int iy = site / 18, ix = site - iy*18;
            const ushort_t* g = xsel_base + (size_t)(iy*66 + ix)*256 + cb*32 + l4*8;
            gl2lds16(g, &sIn[r*512]);
        }
        for (int r = wave; r < 18; r += 4) {
            const ushort_t* g = wt_base + (size_t)cb*9216 + r*512 + lane*8;
            gl2lds16(g, &sW[r*512]);
        }
        __syncthreads();

        #pragma unroll
        for (int tap = 0; tap < 9; tap++) {
            const int dy = tap / 3, dx = tap % 3;
            short8 B0 = *(const short8*)&sW[(tap*32 +      l15)*32 + quad*8];
            short8 B1 = *(const short8*)&sW[(tap*32 + 16 + l15)*32 + quad*8];
            #pragma unroll
            for (int mi = 0; mi < 4; mi++) {
                int row = wave*4 + mi + dy;
                short8 A = *(const short8*)&sIn[(row*18 + l15 + dx)*32 + quad*8];
                acc[mi][0] = __builtin_amdgcn_mfma_f32_16x16x32_bf16(A, B0, acc[mi][0], 0, 0, 0);
                acc[mi][1] = __builtin_amdgcn_mfma_f32_16x16x32_bf16(A, B1, acc[mi][1], 0, 0, 0);
            }
        }
    }

    int y0 = ty*16, x0 = tx*16;
    const float* xb_ = x   + ((size_t)b << 19);
    float*       ob  = out + ((size_t)b << 19);
    const float* mxb = maxv + (b << 12);
    #pragma unroll
    for (int mi = 0; mi < 4; mi++) {
        int y = y0 + wave*4 + mi;
        int p = (y << 6) + x0 + quad*4;
        float4 mv = *(const float4*)&mxb[p];
        #pragma unroll
        for (int ni = 0; ni < 2; ni++) {
            int o = og*32 + ni*16 + l15;
            float bfo = bf[o];
            float4 xv = *(const float4*)&xb_[((size_t)o << 12) + p];
            float4 r;
            r.x = xv.x + mv.x * (acc[mi][ni][0] + bfo);
            r.y = xv.y + mv.y * (acc[mi][ni][1] + bfo);
            r.z = xv.z + mv.z * (acc[mi][ni][2] + bfo);
            r.w = xv.w + mv.w * (acc[mi][ni][3] + bfo);
            *(float4*)&ob[((size_t)o << 12) + p] = r;
        }
    }
}

extern "C" void kernel_launch(void* const* d_in, const int* in_sizes, int n_in,
                              void* d_out, int out_size, void* d_ws, size_t ws_size,
                              hipStream_t stream) {
    (void)in_sizes; (void)n_in; (void)out_size; (void)ws_size;
    const float* x  = (const float*)d_in[0];
    const float* xf = (const float*)d_in[1];
    const float* xb = (const float*)d_in[2];
    const float* Wq = (const float*)d_in[3];
    const float* bq = (const float*)d_in[4];
    const float* Wk = (const float*)d_in[5];
    const float* bk = (const float*)d_in[6];
    const float* Wv = (const float*)d_in[7];
    const float* bv = (const float*)d_in[8];
    const float* Wf = (const float*)d_in[9];
    const float* bf = (const float*)d_in[10];
    float* out = (float*)d_out;

    float* ws   = (float*)d_ws;
    float* Qt   = ws;                          // 262144 f
    float* Kt   = Qt + 262144;                 // 262144 f
    float* V    = Kt + 262144;                 // 2097152 f (pos-major [b][p][c])
    float* mx   = V  + 2097152;                // 16384 f
    int*   idxv = (int*)(mx + 16384);          // 16384 i
    int*   gN   = (int*)(idxv + 16384);        // 4 i (pad)
    int*   gList= gN + 4;                      // 16384 i
    ushort_t* Qs   = (ushort_t*)(gList + 16384); // 1048576 sh
    ushort_t* KB   = Qs + 1048576;             // 1572864 sh
    ushort_t* xsel = KB + 1572864;             // 4460544 sh
    ushort_t* Wt   = xsel + 4460544;           // 294912 sh

    hipMemsetAsync(gN, 0, sizeof(int), stream);
    hipLaunchKernelGGL(prep_kernel,   dim3(658), dim3(256), 0, stream,
                       x, xf, Wq, bq, Wk, bk, Wf, Qt, Kt, Qs, KB, xsel, Wt);
    hipLaunchKernelGGL(v_kernel,      dim3(256), dim3(256), 0, stream, xb, Wv, bv, V);
    hipLaunchKernelGGL(att_kernel,    dim3(256), dim3(512), 0, stream, Qs, KB, mx, idxv, gN, gList);
    hipLaunchKernelGGL(fixup2_kernel, dim3(64),  dim3(256), 0, stream, Qt, Kt, gN, gList, mx, idxv);
    hipLaunchKernelGGL(gather_kernel, dim3(256), dim3(256), 0, stream, V, idxv, xsel);
    hipLaunchKernelGGL(conv_kernel,   dim3(256), dim3(256), 0, stream, x, xsel, Wt, bf, mx, out);
}

// Round 10
// 173.560 us; speedup vs baseline: 1.2387x; 1.1794x over previous
//
#include <hip/hip_runtime.h>

#define HW 4096
#define CC 128
#define MARGIN 2e-3f

typedef unsigned short ushort_t;
typedef unsigned int uint_t;
typedef __attribute__((ext_vector_type(8))) short short8;
typedef __attribute__((ext_vector_type(4))) float f32x4;

__device__ __forceinline__ float dot4(float4 a, float4 b) {
    return (a.x*b.x + a.y*b.y) + (a.z*b.z + a.w*b.w);
}

__device__ __forceinline__ ushort_t f2bf(float f) {
    union { float f; uint_t u; } cv; cv.f = f;
    uint_t r = cv.u + 0x7fffu + ((cv.u >> 16) & 1u);
    return (ushort_t)(r >> 16);
}

__device__ __forceinline__ float bf2f(ushort_t h) {
    union { uint_t u; float f; } cv; cv.u = ((uint_t)h) << 16;
    return cv.f;
}

__device__ __forceinline__ void store16(ushort_t* dst, const ushort_t* s) {
    union { ushort_t s[8]; uint4 v; } a, b;
    #pragma unroll
    for (int j = 0; j < 8; j++) { a.s[j] = s[j]; b.s[j] = s[8+j]; }
    *(uint4*)dst = a.v;
    *(uint4*)(dst + 8) = b.v;
}

__device__ __forceinline__ void gl2lds16(const ushort_t* g, ushort_t* l) {
    __builtin_amdgcn_global_load_lds(
        (const __attribute__((address_space(1))) unsigned int*)g,
        (__attribute__((address_space(3))) unsigned int*)l, 16, 0, 0);
}

// ---------- Kernel 1: fused prep (qk+split | v | xt | border | wt) ----------
// grid 1810: [0,256) qk, [256,1280) v, [1280,1536) xt, [1536,1666) border, [1666,1810) wt
__global__ __launch_bounds__(256) void prep_kernel(
    const float* __restrict__ x, const float* __restrict__ xf, const float* __restrict__ xb,
    const float* __restrict__ Wq, const float* __restrict__ bq,
    const float* __restrict__ Wk, const float* __restrict__ bk,
    const float* __restrict__ Wv, const float* __restrict__ bv,
    const float* __restrict__ Wf,
    float* __restrict__ Qt, float* __restrict__ Kt, float* __restrict__ V,
    ushort_t* __restrict__ Qs, ushort_t* __restrict__ KB,
    ushort_t* __restrict__ xsel, ushort_t* __restrict__ Wt)
{
    __shared__ __align__(16) unsigned char smem[16704];
    int bid = blockIdx.x;
    int tid = threadIdx.x;

    if (bid < 256) {
        // ---- qk: Q/K 1x1 conv, 2-way channel split + LDS combine ----
        bool isQ = bid < 128;
        int sub = bid & 127;
        int b = sub >> 5, pt = sub & 31;          // 32 blocks/batch x 128 pos
        const float* src  = isQ ? xf : x;
        const float* W    = isQ ? Wq : Wk;
        const float* bias = isQ ? bq : bk;
        int ph = tid >> 7, pl = tid & 127;        // ph: channel half (wave-uniform)
        int p = pt*128 + pl;
        int pg = (b << 12) + p;
        const float* sp = src + ((size_t)b << 19) + p + ((size_t)(ph*64) << 12);

        float acc[16];
        #pragma unroll
        for (int o = 0; o < 16; o++) acc[o] = ph ? 0.f : bias[o];

        for (int cc = 0; cc < 64; cc += 4) {
            float x0 = sp[(size_t)(cc+0) << 12];
            float x1 = sp[(size_t)(cc+1) << 12];
            float x2 = sp[(size_t)(cc+2) << 12];
            float x3 = sp[(size_t)(cc+3) << 12];
            #pragma unroll
            for (int o = 0; o < 16; o++) {
                float4 w = *(const float4*)&W[o*128 + ph*64 + cc];   // uniform -> s_load
                acc[o] += w.x*x0 + w.y*x1 + w.z*x2 + w.w*x3;
            }
        }

        float* sAcc = (float*)smem;               // [128][17] padded
        if (ph) {
            #pragma unroll
            for (int o = 0; o < 16; o++) sAcc[pl*17 + o] = acc[o];
        }
        __syncthreads();
        if (!ph) {
            #pragma unroll
            for (int o = 0; o < 16; o++) acc[o] += sAcc[pl*17 + o];

            float* dstF = isQ ? Qt : Kt;
            float4* df = (float4*)(dstF + (size_t)pg * 16);
            df[0] = make_float4(acc[0],acc[1],acc[2],acc[3]);
            df[1] = make_float4(acc[4],acc[5],acc[6],acc[7]);
            df[2] = make_float4(acc[8],acc[9],acc[10],acc[11]);
            df[3] = make_float4(acc[12],acc[13],acc[14],acc[15]);

            ushort_t h[16], m[16], l[16];
            #pragma unroll
            for (int d = 0; d < 16; d++) {
                h[d] = f2bf(acc[d]);
                float r1 = acc[d] - bf2f(h[d]);
                m[d] = f2bf(r1);
                l[d] = f2bf(r1 - bf2f(m[d]));
            }
            if (isQ) {
                ushort_t* o_ = Qs + (size_t)pg*64;    // [h|m|h|l]
                store16(o_,      h);
                store16(o_ + 16, m);
                store16(o_ + 32, h);
                store16(o_ + 48, l);
            } else {
                int u = b*256 + (p >> 4);
                int n = p & 15;
                ushort_t* o_ = KB + (size_t)u*1536 + n*32;
                store16(o_,        h); store16(o_ + 16,   h);   // pass0 [kh|kh]
                store16(o_ + 512,  m); store16(o_ + 528,  m);   // pass1 [km|km]
                store16(o_ + 1024, l); store16(o_ + 1040, h);   // pass2 [kl|kh]
            }
        }
    } else if (bid < 1280) {
        // ---- v: V = Wv * xb + bv -> pos-major [b][p][c]; 8 och x 256 pos/block ----
        int vbid = bid - 256;
        int b = vbid >> 8, og = (vbid >> 4) & 15, pt = vbid & 15;
        float* sW = (float*)smem;                  // 8 x 128
        for (int e = tid; e < 1024; e += 256) sW[e] = Wv[og*1024 + e];
        __syncthreads();

        int p = pt*256 + tid;
        const float* sp = xb + ((size_t)b << 19) + p;

        float acc[8];
        #pragma unroll
        for (int j = 0; j < 8; j++) acc[j] = 0.f;

        for (int c4 = 0; c4 < 128; c4 += 4) {
            float x0 = sp[(size_t)(c4+0) << 12];
            float x1 = sp[(size_t)(c4+1) << 12];
            float x2 = sp[(size_t)(c4+2) << 12];
            float x3 = sp[(size_t)(c4+3) << 12];
            #pragma unroll
            for (int j = 0; j < 8; j++) {
                float4 w = *(const float4*)&sW[j*128 + c4];
                acc[j] += w.x*x0 + w.y*x1 + w.z*x2 + w.w*x3;
            }
        }
        float* vr = V + ((size_t)((b << 12) + p))*128 + og*8;
        float4 r0 = make_float4(acc[0]+bv[og*8+0], acc[1]+bv[og*8+1],
                                acc[2]+bv[og*8+2], acc[3]+bv[og*8+3]);
        float4 r1 = make_float4(acc[4]+bv[og*8+4], acc[5]+bv[og*8+5],
                                acc[6]+bv[og*8+6], acc[7]+bv[og*8+7]);
        *(float4*)vr = r0;
        *(float4*)(vr + 4) = r1;
    } else if (bid < 1536) {
        // ---- xt: x f32 [c][y][x] -> xsel[b][y+1][x+1][c] bf16 (c<128) ----
        ushort_t* sT = (ushort_t*)smem;    // 64*130
        int xbid = bid - 1280;
        int b = xbid >> 6, y = xbid & 63;
        int cq = tid >> 6, xx = tid & 63;
        const float* src = x + ((size_t)b << 19) + (y << 6) + xx;
        #pragma unroll 4
        for (int k = 0; k < 32; k++) {
            int c = cq*32 + k;
            sT[xx*130 + c] = f2bf(src[(size_t)c << 12]);
        }
        __syncthreads();
        uint_t* dst = (uint_t*)(xsel + ((size_t)(b*4356 + (y+1)*66 + 1))*256);
        #pragma unroll
        for (int k = 0; k < 16; k++) {
            int idx = k*256 + tid;
            int s = idx >> 6, u = idx & 63;
            uint_t v = *(const uint_t*)&sT[s*130 + u*2];
            dst[s*128 + u] = v;
        }
    } else if (bid < 1666) {
        // ---- border: zero 66x66 border sites of xsel ----
        int g = (bid - 1536) * 256 + tid;
        if (g < 33280) {
            int b = g / 8320;
            int rem = g - b * 8320;
            int si = rem >> 5;
            int ch = rem & 31;
            int y, xx;
            if (si < 66)      { y = 0;  xx = si; }
            else if (si < 132){ y = 65; xx = si - 66; }
            else { int t = si - 132; y = 1 + (t >> 1); xx = (t & 1) ? 65 : 0; }
            int site = y * 66 + xx;
            uint4* dst = (uint4*)(xsel + ((size_t)(b*4356 + site))*256);
            dst[ch] = make_uint4(0,0,0,0);
        }
    } else {
        // ---- wt: Wf f32 -> bf16 [og][cb][tap][o32][ci32] ----
        int t = (bid - 1666) * 256 + tid;
        if (t < 36864) {
            int cg = t & 3;
            int o = (t >> 2) & 31;
            int tc = t >> 7;
            int tap = tc % 9;
            int rest = tc / 9;
            int cb = rest & 7, og = rest >> 3;
            union { ushort_t s[8]; uint4 v; } pk;
            #pragma unroll
            for (int j = 0; j < 8; j++) {
                int ci = cg*8 + j;
                pk.s[j] = f2bf(Wf[(size_t)(og*32 + o)*2304 + (cb*32 + ci)*9 + tap]);
            }
            *(uint4*)(Wt + (size_t)t*8) = pk.v;
        }
    }
}

// ---------- Kernel 2: MFMA max/argmax over ALL q; writes maxv/idxv + flags ----------
// grid 256 = b(4) x kg(64); block 512 = 8 waves; block: 64 k x 4096 q.
__global__ __launch_bounds__(512, 2) void att_kernel(
    const ushort_t* __restrict__ Qs, const ushort_t* __restrict__ KB,
    float* __restrict__ maxv, int* __restrict__ idxv,
    int* __restrict__ gN, int* __restrict__ gList)
{
    __shared__ float sM1[64*33];
    __shared__ int   sI1[64*33];
    __shared__ float sM2[64*33];

    int bid = blockIdx.x;
    int kg = bid & 63, b = bid >> 6;
    int tid = threadIdx.x;
    int wave = tid >> 6, lane = tid & 63;
    int l15 = lane & 15, quad = lane >> 4;

    short8 Bf[4][3];
    const ushort_t* kb = KB + ((size_t)((b*256 + kg*4)*3))*512 + l15*32 + quad*8;
    #pragma unroll
    for (int t = 0; t < 4; t++)
        #pragma unroll
        for (int p = 0; p < 3; p++)
            Bf[t][p] = *(const short8*)(kb + (size_t)(t*3 + p)*512);

    const ushort_t* qbase = Qs + ((size_t)(b*4096 + wave*512 + l15))*64 + quad*8;

    float m1[4], m2[4]; int i1[4];
    #pragma unroll
    for (int t = 0; t < 4; t++) { m1[t] = -1e30f; m2[t] = -1e30f; i1[t] = 0; }

    for (int it = 0; it < 32; it++) {
        const ushort_t* aptr = qbase + it*1024;
        short8 A1 = *(const short8*)aptr;
        short8 A2 = *(const short8*)(aptr + 32);
        f32x4 acc[4];
        #pragma unroll
        for (int t = 0; t < 4; t++) {
            acc[t] = (f32x4)0.f;
            acc[t] = __builtin_amdgcn_mfma_f32_16x16x32_bf16(A1, Bf[t][0], acc[t], 0, 0, 0);
            acc[t] = __builtin_amdgcn_mfma_f32_16x16x32_bf16(A1, Bf[t][1], acc[t], 0, 0, 0);
            acc[t] = __builtin_amdgcn_mfma_f32_16x16x32_bf16(A2, Bf[t][2], acc[t], 0, 0, 0);
        }
        int q0 = wave*512 + it*16 + quad*4;
        #pragma unroll
        for (int r = 0; r < 4; r++) {
            int cand = q0 + r;
            #pragma unroll
            for (int t = 0; t < 4; t++) {
                float d = acc[t][r];
                float old1 = m1[t];
                bool gt = d > old1;
                m1[t] = gt ? d : old1;
                i1[t] = gt ? cand : i1[t];
                m2[t] = __builtin_amdgcn_fmed3f(d, old1, m2[t]);
            }
        }
    }

    #pragma unroll
    for (int t = 0; t < 4; t++) {
        int kl_ = t*16 + l15;
        int slot = wave*4 + quad;
        sM1[kl_*33 + slot] = m1[t];
        sI1[kl_*33 + slot] = i1[t];
        sM2[kl_*33 + slot] = m2[t];
    }
    __syncthreads();
    if (tid < 64) {
        float M1 = -1e30f; int I1 = 0x7fffffff;
        for (int s = 0; s < 32; s++) {
            float m = sM1[tid*33 + s]; int i = sI1[tid*33 + s];
            if (m > M1 || (m == M1 && i < I1)) { M1 = m; I1 = i; }
        }
        float M2 = -1e30f;
        for (int s = 0; s < 32; s++) {
            float m = sM1[tid*33 + s]; int i = sI1[tid*33 + s];
            float cnd = (i == I1) ? sM2[tid*33 + s] : m;
            M2 = fmaxf(M2, cnd);
        }
        int row = (b << 12) + kg*64 + tid;
        maxv[row] = M1; idxv[row] = I1;
        if (M1 - M2 < MARGIN) {
            int p = atomicAdd(gN, 1);
            gList[p] = row;
        }
    }
}

// ---------- Kernel 3: exact f32 rescan of flagged rows (parallel reduce) ----------
__global__ __launch_bounds__(256) void fixup2_kernel(
    const float* __restrict__ Qt, const float* __restrict__ Kt,
    const int* __restrict__ gN, const int* __restrict__ gList,
    float* __restrict__ maxv, int* __restrict__ idxv)
{
    __shared__ float sRm[256];
    __shared__ int   sRi[256];
    int n = *gN;
    int tid = threadIdx.x;
    for (int e = blockIdx.x; e < n; e += 64) {
        int r2 = gList[e];
        int b2 = r2 >> 12, k2 = r2 & 4095;
        const float4* Kp = (const float4*)(Kt + ((size_t)(b2*4096 + k2))*16);
        float4 ka = Kp[0], kbv = Kp[1], kc = Kp[2], kd = Kp[3];
        const float4* Qp = (const float4*)(Qt + ((size_t)b2*4096)*16);
        float m = -1e30f; int i = 0;
        #pragma unroll 4
        for (int j = 0; j < 16; j++) {
            int q = tid*16 + j;
            float4 qa = Qp[q*4+0], qb = Qp[q*4+1], qc = Qp[q*4+2], qd = Qp[q*4+3];
            float d = (dot4(ka,qa) + dot4(kbv,qb)) + (dot4(kc,qc) + dot4(kd,qd));
            if (d > m) { m = d; i = q; }
        }
        sRm[tid] = m; sRi[tid] = i;
        __syncthreads();
        #pragma unroll
        for (int s = 128; s > 0; s >>= 1) {
            if (tid < s) {
                float mo = sRm[tid+s]; int io = sRi[tid+s];
                if (mo > sRm[tid] || (mo == sRm[tid] && io < sRi[tid])) {
                    sRm[tid] = mo; sRi[tid] = io;
                }
            }
            __syncthreads();
        }
        if (tid == 0) { maxv[r2] = sRm[0]; idxv[r2] = sRi[0]; }
        __syncthreads();
    }
}

// ---------- Kernel 4: gather V rows (pos-major) -> xsel bf16 ----------
__global__ __launch_bounds__(256) void gather_kernel(
    const float* __restrict__ V, const int* __restrict__ idxv,
    ushort_t* __restrict__ xsel)
{
    int bid = blockIdx.x;
    int b = bid >> 6, pt = bid & 63;
    int tid = threadIdx.x;
    int pp = tid >> 2, cq = tid & 3;
    int p = pt*64 + pp;
    int ip = idxv[(b << 12) + p];
    const float* vrow = V + ((size_t)((b << 12) + ip))*128 + cq*32;
    int site = ((p >> 6) + 1)*66 + (p & 63) + 1;
    ushort_t* dst = xsel + ((size_t)(b*4356 + site))*256 + 128 + cq*32;
    #pragma unroll
    for (int k = 0; k < 4; k++) {
        float4 a = *(const float4*)(vrow + k*8);
        float4 c = *(const float4*)(vrow + k*8 + 4);
        union { ushort_t s[8]; uint4 v; } pk;
        pk.s[0] = f2bf(a.x); pk.s[1] = f2bf(a.y); pk.s[2] = f2bf(a.z); pk.s[3] = f2bf(a.w);
        pk.s[4] = f2bf(c.x); pk.s[5] = f2bf(c.y); pk.s[6] = f2bf(c.z); pk.s[7] = f2bf(c.w);
        *(uint4*)(dst + k*8) = pk.v;
    }
}

// ---------- Kernel 5: 3x3 conv as bf16 MFMA shift-GEMM ----------
__global__ __launch_bounds__(256) void conv_kernel(
    const float* __restrict__ x, const ushort_t* __restrict__ xsel,
    const ushort_t* __restrict__ Wt, const float* __restrict__ bf,
    const float* __restrict__ maxv, float* __restrict__ out)
{
    __shared__ __align__(16) ushort_t sIn[336*32];
    __shared__ __align__(16) ushort_t sW[9*32*32];

    int bid = blockIdx.x;
    int og = bid & 3, tx = (bid >> 2) & 3, ty = (bid >> 4) & 3, b = bid >> 6;
    int tid = threadIdx.x;
    int wave = tid >> 6, lane = tid & 63;
    int l15 = lane & 15, quad = lane >> 4;

    const ushort_t* xsel_base = xsel + ((size_t)(b*4356 + (ty*16)*66 + tx*16))*256;
    const ushort_t* wt_base   = Wt + (size_t)og*8*9216;

    f32x4 acc[4][2];
    #pragma unroll
    for (int mi = 0; mi < 4; mi++)
        #pragma unroll
        for (int ni = 0; ni < 2; ni++) acc[mi][ni] = (f32x4)0.f;

    int l4q = lane >> 2, l4 = lane & 3;

    for (int cb = 0; cb < 8; cb++) {
        if (cb) __syncthreads();
        for (int r = wave; r < 21; r += 4) {
            int site = r*16 + l4q;
            int iy = site / 18, ix = site - iy*18;
            const ushort_t* g = xsel_base + (size_t)(iy*66 + ix)*256 + cb*32 + l4*8;
            gl2lds16(g, &sIn[r*512]);
        }
        for (int r = wave; r < 18; r += 4) {
            const ushort_t* g = wt_base + (size_t)cb*9216 + r*512 + lane*8;
            gl2lds16(g, &sW[r*512]);
        }
        __syncthreads();

        #pragma unroll
        for (int tap = 0; tap < 9; tap++) {
            const int dy = tap / 3, dx = tap % 3;
            short8 B0 = *(const short8*)&sW[(tap*32 +      l15)*32 + quad*8];
            short8 B1 = *(const short8*)&sW[(tap*32 + 16 + l15)*32 + quad*8];
            #pragma unroll
            for (int mi = 0; mi < 4; mi++) {
                int row = wave*4 + mi + dy;
                short8 A = *(const short8*)&sIn[(row*18 + l15 + dx)*32 + quad*8];
                acc[mi][0] = __builtin_amdgcn_mfma_f32_16x16x32_bf16(A, B0, acc[mi][0], 0, 0, 0);
                acc[mi][1] = __builtin_amdgcn_mfma_f32_16x16x32_bf16(A, B1, acc[mi][1], 0, 0, 0);
            }
        }
    }

    int y0 = ty*16, x0 = tx*16;
    const float* xb_ = x   + ((size_t)b << 19);
    float*       ob  = out + ((size_t)b << 19);
    const float* mxb = maxv + (b << 12);
    #pragma unroll
    for (int mi = 0; mi < 4; mi++) {
        int y = y0 + wave*4 + mi;
        int p = (y << 6) + x0 + quad*4;
        float4 mv = *(const float4*)&mxb[p];
        #pragma unroll
        for (int ni = 0; ni < 2; ni++) {
            int o = og*32 + ni*16 + l15;
            float bfo = bf[o];
            float4 xv = *(const float4*)&xb_[((size_t)o << 12) + p];
            float4 r;
            r.x = xv.x + mv.x * (acc[mi][ni][0] + bfo);
            r.y = xv.y + mv.y * (acc[mi][ni][1] + bfo);
            r.z = xv.z + mv.z * (acc[mi][ni][2] + bfo);
            r.w = xv.w + mv.w * (acc[mi][ni][3] + bfo);
            *(float4*)&ob[((size_t)o << 12) + p] = r;
        }
    }
}

extern "C" void kernel_launch(void* const* d_in, const int* in_sizes, int n_in,
                              void* d_out, int out_size, void* d_ws, size_t ws_size,
                              hipStream_t stream) {
    (void)in_sizes; (void)n_in; (void)out_size; (void)ws_size;
    const float* x  = (const float*)d_in[0];
    const float* xf = (const float*)d_in[1];
    const float* xb = (const float*)d_in[2];
    const float* Wq = (const float*)d_in[3];
    const float* bq = (const float*)d_in[4];
    const float* Wk = (const float*)d_in[5];
    const float* bk = (const float*)d_in[6];
    const float* Wv = (const float*)d_in[7];
    const float* bv = (const float*)d_in[8];
    const float* Wf = (const float*)d_in[9];
    const float* bf = (const float*)d_in[10];
    float* out = (float*)d_out;

    float* ws   = (float*)d_ws;
    float* Qt   = ws;                          // 262144 f
    float* Kt   = Qt + 262144;                 // 262144 f
    float* V    = Kt + 262144;                 // 2097152 f (pos-major [b][p][c])
    float* mx   = V  + 2097152;                // 16384 f
    int*   idxv = (int*)(mx + 16384);          // 16384 i
    int*   gN   = (int*)(idxv + 16384);        // 4 i (pad)
    int*   gList= gN + 4;                      // 16384 i
    ushort_t* Qs   = (ushort_t*)(gList + 16384); // 1048576 sh
    ushort_t* KB   = Qs + 1048576;             // 1572864 sh
    ushort_t* xsel = KB + 1572864;             // 4460544 sh
    ushort_t* Wt   = xsel + 4460544;           // 294912 sh

    hipMemsetAsync(gN, 0, sizeof(int), stream);
    hipLaunchKernelGGL(prep_kernel,   dim3(1810), dim3(256), 0, stream,
                       x, xf, xb, Wq, bq, Wk, bk, Wv, bv, Wf,
                       Qt, Kt, V, Qs, KB, xsel, Wt);
    hipLaunchKernelGGL(att_kernel,    dim3(256), dim3(512), 0, stream, Qs, KB, mx, idxv, gN, gList);
    hipLaunchKernelGGL(fixup2_kernel, dim3(64),  dim3(256), 0, stream, Qt, Kt, gN, gList, mx, idxv);
    hipLaunchKernelGGL(gather_kernel, dim3(256), dim3(256), 0, stream, V, idxv, xsel);
    hipLaunchKernelGGL(conv_kernel,   dim3(256), dim3(256), 0, stream, x, xsel, Wt, bf, mx, out);
}

// Round 11
// 169.993 us; speedup vs baseline: 1.2647x; 1.0210x over previous
//
#include <hip/hip_runtime.h>

#define HW 4096
#define CC 128
#define MARGIN 2e-3f

typedef unsigned short ushort_t;
typedef unsigned int uint_t;
typedef __attribute__((ext_vector_type(8))) short short8;
typedef __attribute__((ext_vector_type(4))) float f32x4;

__device__ __forceinline__ float dot4(float4 a, float4 b) {
    return (a.x*b.x + a.y*b.y) + (a.z*b.z + a.w*b.w);
}

__device__ __forceinline__ ushort_t f2bf(float f) {
    union { float f; uint_t u; } cv; cv.f = f;
    uint_t r = cv.u + 0x7fffu + ((cv.u >> 16) & 1u);
    return (ushort_t)(r >> 16);
}

__device__ __forceinline__ float bf2f(ushort_t h) {
    union { uint_t u; float f; } cv; cv.u = ((uint_t)h) << 16;
    return cv.f;
}

__device__ __forceinline__ void store16(ushort_t* dst, const ushort_t* s) {
    union { ushort_t s[8]; uint4 v; } a, b;
    #pragma unroll
    for (int j = 0; j < 8; j++) { a.s[j] = s[j]; b.s[j] = s[8+j]; }
    *(uint4*)dst = a.v;
    *(uint4*)(dst + 8) = b.v;
}

__device__ __forceinline__ void gl2lds16(const ushort_t* g, ushort_t* l) {
    __builtin_amdgcn_global_load_lds(
        (const __attribute__((address_space(1))) unsigned int*)g,
        (__attribute__((address_space(3))) unsigned int*)l, 16, 0, 0);
}

// ---------- Kernel 1: fused prep (qk+split | v | xt | border | wt) ----------
// grid 2066: [0,512) qk, [512,1536) v, [1536,1792) xt, [1792,1922) border, [1922,2066) wt
__global__ __launch_bounds__(256) void prep_kernel(
    const float* __restrict__ x, const float* __restrict__ xf, const float* __restrict__ xb,
    const float* __restrict__ Wq, const float* __restrict__ bq,
    const float* __restrict__ Wk, const float* __restrict__ bk,
    const float* __restrict__ Wv, const float* __restrict__ bv,
    const float* __restrict__ Wf,
    float* __restrict__ Qt, float* __restrict__ Kt, float* __restrict__ V,
    ushort_t* __restrict__ Qs, ushort_t* __restrict__ KB,
    ushort_t* __restrict__ xsel, ushort_t* __restrict__ Wt)
{
    __shared__ __align__(16) unsigned char smem[16704];
    int bid = blockIdx.x;
    int tid = threadIdx.x;

    if (bid < 512) {
        // ---- qk: Q/K 1x1 conv, 4-way channel split (wave = quarter) + LDS combine ----
        bool isQ = bid < 256;
        int sub = bid & 255;
        int b = sub >> 6, pt = sub & 63;          // 64 pos per block
        const float* src  = isQ ? xf : x;
        const float* W    = isQ ? Wq : Wk;
        const float* bias = isQ ? bq : bk;
        int ph = tid >> 6, pl = tid & 63;         // ph: channel quarter (wave-uniform)
        int p = pt*64 + pl;
        int pg = (b << 12) + p;
        const float* sp = src + ((size_t)b << 19) + p + ((size_t)(ph*32) << 12);

        float acc[16];
        #pragma unroll
        for (int o = 0; o < 16; o++) acc[o] = ph ? 0.f : bias[o];

        for (int cc = 0; cc < 32; cc += 4) {
            float x0 = sp[(size_t)(cc+0) << 12];
            float x1 = sp[(size_t)(cc+1) << 12];
            float x2 = sp[(size_t)(cc+2) << 12];
            float x3 = sp[(size_t)(cc+3) << 12];
            #pragma unroll
            for (int o = 0; o < 16; o++) {
                float4 w = *(const float4*)&W[o*128 + ph*32 + cc];   // uniform -> s_load
                acc[o] += w.x*x0 + w.y*x1 + w.z*x2 + w.w*x3;
            }
        }

        float* sAcc = (float*)smem;               // [3][64][17] floats = 13056 B
        if (ph) {
            float* dst = sAcc + (ph-1)*1088 + pl*17;
            #pragma unroll
            for (int o = 0; o < 16; o++) dst[o] = acc[o];
        }
        __syncthreads();
        if (!ph) {
            const float* s0 = sAcc + pl*17;
            const float* s1 = sAcc + 1088 + pl*17;
            const float* s2 = sAcc + 2176 + pl*17;
            #pragma unroll
            for (int o = 0; o < 16; o++) acc[o] += s0[o] + s1[o] + s2[o];

            float* dstF = isQ ? Qt : Kt;
            float4* df = (float4*)(dstF + (size_t)pg * 16);
            df[0] = make_float4(acc[0],acc[1],acc[2],acc[3]);
            df[1] = make_float4(acc[4],acc[5],acc[6],acc[7]);
            df[2] = make_float4(acc[8],acc[9],acc[10],acc[11]);
            df[3] = make_float4(acc[12],acc[13],acc[14],acc[15]);

            ushort_t h[16], m[16], l[16];
            #pragma unroll
            for (int d = 0; d < 16; d++) {
                h[d] = f2bf(acc[d]);
                float r1 = acc[d] - bf2f(h[d]);
                m[d] = f2bf(r1);
                l[d] = f2bf(r1 - bf2f(m[d]));
            }
            if (isQ) {
                ushort_t* o_ = Qs + (size_t)pg*64;    // [h|m|h|l]
                store16(o_,      h);
                store16(o_ + 16, m);
                store16(o_ + 32, h);
                store16(o_ + 48, l);
            } else {
                int u = b*256 + (p >> 4);
                int n = p & 15;
                ushort_t* o_ = KB + (size_t)u*1536 + n*32;
                store16(o_,        h); store16(o_ + 16,   h);   // pass0 [kh|kh]
                store16(o_ + 512,  m); store16(o_ + 528,  m);   // pass1 [km|km]
                store16(o_ + 1024, l); store16(o_ + 1040, h);   // pass2 [kl|kh]
            }
        }
    } else if (bid < 1536) {
        // ---- v: V = Wv * xb + bv -> pos-major [b][p][c]; 8 och x 256 pos/block ----
        int vbid = bid - 512;
        int b = vbid >> 8, og = (vbid >> 4) & 15, pt = vbid & 15;
        float* sW = (float*)smem;                  // 8 x 128
        for (int e = tid; e < 1024; e += 256) sW[e] = Wv[og*1024 + e];
        __syncthreads();

        int p = pt*256 + tid;
        const float* sp = xb + ((size_t)b << 19) + p;

        float acc[8];
        #pragma unroll
        for (int j = 0; j < 8; j++) acc[j] = 0.f;

        for (int c4 = 0; c4 < 128; c4 += 4) {
            float x0 = sp[(size_t)(c4+0) << 12];
            float x1 = sp[(size_t)(c4+1) << 12];
            float x2 = sp[(size_t)(c4+2) << 12];
            float x3 = sp[(size_t)(c4+3) << 12];
            #pragma unroll
            for (int j = 0; j < 8; j++) {
                float4 w = *(const float4*)&sW[j*128 + c4];
                acc[j] += w.x*x0 + w.y*x1 + w.z*x2 + w.w*x3;
            }
        }
        float* vr = V + ((size_t)((b << 12) + p))*128 + og*8;
        float4 r0 = make_float4(acc[0]+bv[og*8+0], acc[1]+bv[og*8+1],
                                acc[2]+bv[og*8+2], acc[3]+bv[og*8+3]);
        float4 r1 = make_float4(acc[4]+bv[og*8+4], acc[5]+bv[og*8+5],
                                acc[6]+bv[og*8+6], acc[7]+bv[og*8+7]);
        *(float4*)vr = r0;
        *(float4*)(vr + 4) = r1;
    } else if (bid < 1792) {
        // ---- xt: x f32 [c][y][x] -> xsel[b][y+1][x+1][c] bf16 (c<128) ----
        ushort_t* sT = (ushort_t*)smem;    // 64*130
        int xbid = bid - 1536;
        int b = xbid >> 6, y = xbid & 63;
        int cq = tid >> 6, xx = tid & 63;
        const float* src = x + ((size_t)b << 19) + (y << 6) + xx;
        #pragma unroll 4
        for (int k = 0; k < 32; k++) {
            int c = cq*32 + k;
            sT[xx*130 + c] = f2bf(src[(size_t)c << 12]);
        }
        __syncthreads();
        uint_t* dst = (uint_t*)(xsel + ((size_t)(b*4356 + (y+1)*66 + 1))*256);
        #pragma unroll
        for (int k = 0; k < 16; k++) {
            int idx = k*256 + tid;
            int s = idx >> 6, u = idx & 63;
            uint_t v = *(const uint_t*)&sT[s*130 + u*2];
            dst[s*128 + u] = v;
        }
    } else if (bid < 1922) {
        // ---- border: zero 66x66 border sites of xsel ----
        int g = (bid - 1792) * 256 + tid;
        if (g < 33280) {
            int b = g / 8320;
            int rem = g - b * 8320;
            int si = rem >> 5;
            int ch = rem & 31;
            int y, xx;
            if (si < 66)      { y = 0;  xx = si; }
            else if (si < 132){ y = 65; xx = si - 66; }
            else { int t = si - 132; y = 1 + (t >> 1); xx = (t & 1) ? 65 : 0; }
            int site = y * 66 + xx;
            uint4* dst = (uint4*)(xsel + ((size_t)(b*4356 + site))*256);
            dst[ch] = make_uint4(0,0,0,0);
        }
    } else {
        // ---- wt: Wf f32 -> bf16 [og][cb][tap][o32][ci32] ----
        int t = (bid - 1922) * 256 + tid;
        if (t < 36864) {
            int cg = t & 3;
            int o = (t >> 2) & 31;
            int tc = t >> 7;
            int tap = tc % 9;
            int rest = tc / 9;
            int cb = rest & 7, og = rest >> 3;
            union { ushort_t s[8]; uint4 v; } pk;
            #pragma unroll
            for (int j = 0; j < 8; j++) {
                int ci = cg*8 + j;
                pk.s[j] = f2bf(Wf[(size_t)(og*32 + o)*2304 + (cb*32 + ci)*9 + tap]);
            }
            *(uint4*)(Wt + (size_t)t*8) = pk.v;
        }
    }
}

// ---------- Kernel 2: MFMA max/argmax over ALL q; writes maxv/idxv + per-row flag ----------
// grid 256 = b(4) x kg(64); block 512 = 8 waves; block: 64 k x 4096 q.
__global__ __launch_bounds__(512, 2) void att_kernel(
    const ushort_t* __restrict__ Qs, const ushort_t* __restrict__ KB,
    float* __restrict__ maxv, int* __restrict__ idxv, int* __restrict__ flags)
{
    __shared__ float sM1[64*33];
    __shared__ int   sI1[64*33];
    __shared__ float sM2[64*33];

    int bid = blockIdx.x;
    int kg = bid & 63, b = bid >> 6;
    int tid = threadIdx.x;
    int wave = tid >> 6, lane = tid & 63;
    int l15 = lane & 15, quad = lane >> 4;

    short8 Bf[4][3];
    const ushort_t* kb = KB + ((size_t)((b*256 + kg*4)*3))*512 + l15*32 + quad*8;
    #pragma unroll
    for (int t = 0; t < 4; t++)
        #pragma unroll
        for (int p = 0; p < 3; p++)
            Bf[t][p] = *(const short8*)(kb + (size_t)(t*3 + p)*512);

    const ushort_t* qbase = Qs + ((size_t)(b*4096 + wave*512 + l15))*64 + quad*8;

    float m1[4], m2[4]; int i1[4];
    #pragma unroll
    for (int t = 0; t < 4; t++) { m1[t] = -1e30f; m2[t] = -1e30f; i1[t] = 0; }

    for (int it = 0; it < 32; it++) {
        const ushort_t* aptr = qbase + it*1024;
        short8 A1 = *(const short8*)aptr;
        short8 A2 = *(const short8*)(aptr + 32);
        f32x4 acc[4];
        #pragma unroll
        for (int t = 0; t < 4; t++) {
            acc[t] = (f32x4)0.f;
            acc[t] = __builtin_amdgcn_mfma_f32_16x16x32_bf16(A1, Bf[t][0], acc[t], 0, 0, 0);
            acc[t] = __builtin_amdgcn_mfma_f32_16x16x32_bf16(A1, Bf[t][1], acc[t], 0, 0, 0);
            acc[t] = __builtin_amdgcn_mfma_f32_16x16x32_bf16(A2, Bf[t][2], acc[t], 0, 0, 0);
        }
        int q0 = wave*512 + it*16 + quad*4;
        #pragma unroll
        for (int r = 0; r < 4; r++) {
            int cand = q0 + r;
            #pragma unroll
            for (int t = 0; t < 4; t++) {
                float d = acc[t][r];
                float old1 = m1[t];
                bool gt = d > old1;
                m1[t] = gt ? d : old1;
                i1[t] = gt ? cand : i1[t];
                m2[t] = __builtin_amdgcn_fmed3f(d, old1, m2[t]);
            }
        }
    }

    #pragma unroll
    for (int t = 0; t < 4; t++) {
        int kl_ = t*16 + l15;
        int slot = wave*4 + quad;
        sM1[kl_*33 + slot] = m1[t];
        sI1[kl_*33 + slot] = i1[t];
        sM2[kl_*33 + slot] = m2[t];
    }
    __syncthreads();
    if (tid < 64) {
        float M1 = -1e30f; int I1 = 0x7fffffff;
        for (int s = 0; s < 32; s++) {
            float m = sM1[tid*33 + s]; int i = sI1[tid*33 + s];
            if (m > M1 || (m == M1 && i < I1)) { M1 = m; I1 = i; }
        }
        float M2 = -1e30f;
        for (int s = 0; s < 32; s++) {
            float m = sM1[tid*33 + s]; int i = sI1[tid*33 + s];
            float cnd = (i == I1) ? sM2[tid*33 + s] : m;
            M2 = fmaxf(M2, cnd);
        }
        int row = (b << 12) + kg*64 + tid;
        maxv[row] = M1; idxv[row] = I1;
        flags[row] = (M1 - M2 < MARGIN) ? 1 : 0;
    }
}

// ---------- Kernel 3: gather V rows (pos-major) + inline exact rescan of flagged rows ----------
// grid 256 = b(4) x pt(64): 64 positions/block
__global__ __launch_bounds__(256) void gather_kernel(
    const float* __restrict__ V, const float* __restrict__ Qt,
    const float* __restrict__ Kt, const int* __restrict__ idxv,
    const int* __restrict__ flags, float* __restrict__ maxv,
    ushort_t* __restrict__ xsel)
{
    __shared__ int sIdx[64];
    __shared__ int sFlag[64];
    __shared__ int sCnt;
    __shared__ float sRm[256];
    __shared__ int   sRi[256];

    int bid = blockIdx.x;
    int b = bid >> 6, pt = bid & 63;
    int tid = threadIdx.x;
    if (tid == 0) sCnt = 0;
    __syncthreads();
    if (tid < 64) {
        int row = (b << 12) + pt*64 + tid;
        sIdx[tid] = idxv[row];
        if (flags[row]) {
            int s = atomicAdd(&sCnt, 1);
            sFlag[s] = tid;
        }
    }
    __syncthreads();

    // exact f32 rescan for flagged rows (expected 0-1 per block)
    int n = sCnt;
    for (int e = 0; e < n; e++) {
        int local = sFlag[e];
        int row = (b << 12) + pt*64 + local;
        const float4* Kp = (const float4*)(Kt + (size_t)row*16);
        float4 ka = Kp[0], kbv = Kp[1], kc = Kp[2], kd = Kp[3];
        const float4* Qp = (const float4*)(Qt + ((size_t)b << 12)*16);
        float m = -1e30f; int i = 0;
        #pragma unroll 4
        for (int j = 0; j < 16; j++) {
            int q = tid*16 + j;
            float4 qa = Qp[q*4+0], qb = Qp[q*4+1], qc = Qp[q*4+2], qd = Qp[q*4+3];
            float d = (dot4(ka,qa) + dot4(kbv,qb)) + (dot4(kc,qc) + dot4(kd,qd));
            if (d > m) { m = d; i = q; }
        }
        sRm[tid] = m; sRi[tid] = i;
        __syncthreads();
        #pragma unroll
        for (int s = 128; s > 0; s >>= 1) {
            if (tid < s) {
                float mo = sRm[tid+s]; int io = sRi[tid+s];
                if (mo > sRm[tid] || (mo == sRm[tid] && io < sRi[tid])) {
                    sRm[tid] = mo; sRi[tid] = io;
                }
            }
            __syncthreads();
        }
        if (tid == 0) {
            maxv[row] = sRm[0];
            sIdx[local] = sRi[0];
        }
        __syncthreads();
    }

    // gather
    int pp = tid >> 2, cq = tid & 3;
    int p = pt*64 + pp;
    int ip = sIdx[pp];
    const float* vrow = V + ((size_t)((b << 12) + ip))*128 + cq*32;
    int site = ((p >> 6) + 1)*66 + (p & 63) + 1;
    ushort_t* dst = xsel + ((size_t)(b*4356 + site))*256 + 128 + cq*32;
    #pragma unroll
    for (int k = 0; k < 4; k++) {
        float4 a = *(const float4*)(vrow + k*8);
        float4 c = *(const float4*)(vrow + k*8 + 4);
        union { ushort_t s[8]; uint4 v; } pk;
        pk.s[0] = f2bf(a.x); pk.s[1] = f2bf(a.y); pk.s[2] = f2bf(a.z); pk.s[3] = f2bf(a.w);
        pk.s[4] = f2bf(c.x); pk.s[5] = f2bf(c.y); pk.s[6] = f2bf(c.z); pk.s[7] = f2bf(c.w);
        *(uint4*)(dst + k*8) = pk.v;
    }
}

// ---------- Kernel 4: 3x3 conv as bf16 MFMA shift-GEMM, double-buffered LDS ----------
__global__ __launch_bounds__(256) void conv_kernel(
    const float* __restrict__ x, const ushort_t* __restrict__ xsel,
    const ushort_t* __restrict__ Wt, const float* __restrict__ bf,
    const float* __restrict__ maxv, float* __restrict__ out)
{
    __shared__ __align__(16) ushort_t sIn[2][336*32];   // 2 x 21504 B
    __shared__ __align__(16) ushort_t sW[2][9*32*32];   // 2 x 18432 B

    int bid = blockIdx.x;
    int og = bid & 3, tx = (bid >> 2) & 3, ty = (bid >> 4) & 3, b = bid >> 6;
    int tid = threadIdx.x;
    int wave = tid >> 6, lane = tid & 63;
    int l15 = lane & 15, quad = lane >> 4;

    const ushort_t* xsel_base = xsel + ((size_t)(b*4356 + (ty*16)*66 + tx*16))*256;
    const ushort_t* wt_base   = Wt + (size_t)og*8*9216;

    f32x4 acc[4][2];
    #pragma unroll
    for (int mi = 0; mi < 4; mi++)
        #pragma unroll
        for (int ni = 0; ni < 2; ni++) acc[mi][ni] = (f32x4)0.f;

    int l4q = lane >> 2, l4 = lane & 3;

    // stage cb=0 into buf 0
    for (int r = wave; r < 21; r += 4) {
        int site = r*16 + l4q;
        int iy = site / 18, ix = site - iy*18;
        const ushort_t* g = xsel_base + (size_t)(iy*66 + ix)*256 + l4*8;
        gl2lds16(g, &sIn[0][r*512]);
    }
    for (int r = wave; r < 18; r += 4) {
        const ushort_t* g = wt_base + r*512 + lane*8;
        gl2lds16(g, &sW[0][r*512]);
    }
    __syncthreads();

    for (int cb = 0; cb < 8; cb++) {
        int cur = cb & 1;
        if (cb < 7) {
            int nb = cur ^ 1;
            for (int r = wave; r < 21; r += 4) {
                int site = r*16 + l4q;
                int iy = site / 18, ix = site - iy*18;
                const ushort_t* g = xsel_base + (size_t)(iy*66 + ix)*256 + (cb+1)*32 + l4*8;
                gl2lds16(g, &sIn[nb][r*512]);
            }
            for (int r = wave; r < 18; r += 4) {
                const ushort_t* g = wt_base + (size_t)(cb+1)*9216 + r*512 + lane*8;
                gl2lds16(g, &sW[nb][r*512]);
            }
        }

        #pragma unroll
        for (int tap = 0; tap < 9; tap++) {
            const int dy = tap / 3, dx = tap % 3;
            short8 B0 = *(const short8*)&sW[cur][(tap*32 +      l15)*32 + quad*8];
            short8 B1 = *(const short8*)&sW[cur][(tap*32 + 16 + l15)*32 + quad*8];
            #pragma unroll
            for (int mi = 0; mi < 4; mi++) {
                int row = wave*4 + mi + dy;
                short8 A = *(const short8*)&sIn[cur][(row*18 + l15 + dx)*32 + quad*8];
                acc[mi][0] = __builtin_amdgcn_mfma_f32_16x16x32_bf16(A, B0, acc[mi][0], 0, 0, 0);
                acc[mi][1] = __builtin_amdgcn_mfma_f32_16x16x32_bf16(A, B1, acc[mi][1], 0, 0, 0);
            }
        }
        __syncthreads();   // drains prefetch (vmcnt) + protects buffer reuse
    }

    int y0 = ty*16, x0 = tx*16;
    const float* xb_ = x   + ((size_t)b << 19);
    float*       ob  = out + ((size_t)b << 19);
    const float* mxb = maxv + (b << 12);
    #pragma unroll
    for (int mi = 0; mi < 4; mi++) {
        int y = y0 + wave*4 + mi;
        int p = (y << 6) + x0 + quad*4;
        float4 mv = *(const float4*)&mxb[p];
        #pragma unroll
        for (int ni = 0; ni < 2; ni++) {
            int o = og*32 + ni*16 + l15;
            float bfo = bf[o];
            float4 xv = *(const float4*)&xb_[((size_t)o << 12) + p];
            float4 r;
            r.x = xv.x + mv.x * (acc[mi][ni][0] + bfo);
            r.y = xv.y + mv.y * (acc[mi][ni][1] + bfo);
            r.z = xv.z + mv.z * (acc[mi][ni][2] + bfo);
            r.w = xv.w + mv.w * (acc[mi][ni][3] + bfo);
            *(float4*)&ob[((size_t)o << 12) + p] = r;
        }
    }
}

extern "C" void kernel_launch(void* const* d_in, const int* in_sizes, int n_in,
                              void* d_out, int out_size, void* d_ws, size_t ws_size,
                              hipStream_t stream) {
    (void)in_sizes; (void)n_in; (void)out_size; (void)ws_size;
    const float* x  = (const float*)d_in[0];
    const float* xf = (const float*)d_in[1];
    const float* xb = (const float*)d_in[2];
    const float* Wq = (const float*)d_in[3];
    const float* bq = (const float*)d_in[4];
    const float* Wk = (const float*)d_in[5];
    const float* bk = (const float*)d_in[6];
    const float* Wv = (const float*)d_in[7];
    const float* bv = (const float*)d_in[8];
    const float* Wf = (const float*)d_in[9];
    const float* bf = (const float*)d_in[10];
    float* out = (float*)d_out;

    float* ws   = (float*)d_ws;
    float* Qt   = ws;                          // 262144 f
    float* Kt   = Qt + 262144;                 // 262144 f
    float* V    = Kt + 262144;                 // 2097152 f (pos-major [b][p][c])
    float* mx   = V  + 2097152;                // 16384 f
    int*   idxv = (int*)(mx + 16384);          // 16384 i
    int*   flags= (int*)(idxv + 16384);        // 16384 i
    ushort_t* Qs   = (ushort_t*)(flags + 16384); // 1048576 sh
    ushort_t* KB   = Qs + 1048576;             // 1572864 sh
    ushort_t* xsel = KB + 1572864;             // 4460544 sh
    ushort_t* Wt   = xsel + 4460544;           // 294912 sh

    hipLaunchKernelGGL(prep_kernel,   dim3(2066), dim3(256), 0, stream,
                       x, xf, xb, Wq, bq, Wk, bk, Wv, bv, Wf,
                       Qt, Kt, V, Qs, KB, xsel, Wt);
    hipLaunchKernelGGL(att_kernel,    dim3(256), dim3(512), 0, stream, Qs, KB, mx, idxv, flags);
    hipLaunchKernelGGL(gather_kernel, dim3(256), dim3(256), 0, stream,
                       V, Qt, Kt, idxv, flags, mx, xsel);
    hipLaunchKernelGGL(conv_kernel,   dim3(256), dim3(256), 0, stream, x, xsel, Wt, bf, mx, out);
}